// Round 1
// baseline (219.811 us; speedup 1.0000x reference)
//
#include <hip/hip_runtime.h>

// Problem constants
#define NTOT 4096      // T*H*W = 16^3
#define NB   4         // batch
#define CIN  256
#define FF   512
#define COUT 256
#define BN_EPS 1e-5f

#define BM 128
#define BN_ 128
#define BK 16

// C[b][m][n] = epilogue( sum_k A[m][k] * Bm[b][k][n] + bias[m] )
// k1 epilogue: relu(.)                       (HAS_RESID=false)
// k2 epilogue: resid[b][m][n] + relu(.)      (HAS_RESID=true)
template<int KDIM, bool HAS_RESID>
__global__ __launch_bounds__(256, 2)
void gemm_fused(const float* __restrict__ A,
                const float* __restrict__ Bm,
                const float* __restrict__ bias,
                const float* __restrict__ resid,
                float* __restrict__ C,
                int M)
{
    __shared__ float As[BK][BM];   // k-major for float4 reads along rows
    __shared__ float Bs[BK][BN_];

    const int b  = blockIdx.z;
    const int n0 = blockIdx.x * BN_;
    const int m0 = blockIdx.y * BM;
    const int tid = threadIdx.x;
    const int tx = tid & 15;        // 0..15  -> 8 cols: tx*4..+3, +64
    const int ty = (tid >> 4) & 15; // 0..15  -> 8 rows: ty*4..+3, +64

    const float* Bb = Bm + (size_t)b * KDIM * NTOT;

    // A-tile load map: 128 rows x 16 k ; thread loads 2 float4
    const int arow  = tid >> 2;        // 0..63
    const int acol4 = (tid & 3) * 4;   // 0,4,8,12
    // B-tile load map: 16 k x 128 n ; thread loads 2 float4
    const int brow  = tid >> 4;        // 0..15
    const int bcol4 = (tid & 15) * 4;  // 0..60

    float acc[2][2][4][4];
    #pragma unroll
    for (int i = 0; i < 2; ++i)
        #pragma unroll
        for (int j = 0; j < 2; ++j)
            #pragma unroll
            for (int r = 0; r < 4; ++r)
                #pragma unroll
                for (int c = 0; c < 4; ++c) acc[i][j][r][c] = 0.f;

    for (int k0 = 0; k0 < KDIM; k0 += BK) {
        float4 av0 = *reinterpret_cast<const float4*>(&A[(size_t)(m0 + arow) * KDIM + k0 + acol4]);
        float4 av1 = *reinterpret_cast<const float4*>(&A[(size_t)(m0 + arow + 64) * KDIM + k0 + acol4]);
        float4 bv0 = *reinterpret_cast<const float4*>(&Bb[(size_t)(k0 + brow) * NTOT + n0 + bcol4]);
        float4 bv1 = *reinterpret_cast<const float4*>(&Bb[(size_t)(k0 + brow) * NTOT + n0 + bcol4 + 64]);

        __syncthreads();   // previous iteration's LDS reads done
        As[acol4 + 0][arow] = av0.x;  As[acol4 + 1][arow] = av0.y;
        As[acol4 + 2][arow] = av0.z;  As[acol4 + 3][arow] = av0.w;
        As[acol4 + 0][arow + 64] = av1.x;  As[acol4 + 1][arow + 64] = av1.y;
        As[acol4 + 2][arow + 64] = av1.z;  As[acol4 + 3][arow + 64] = av1.w;
        *reinterpret_cast<float4*>(&Bs[brow][bcol4])      = bv0;
        *reinterpret_cast<float4*>(&Bs[brow][bcol4 + 64]) = bv1;
        __syncthreads();

        #pragma unroll
        for (int kk = 0; kk < BK; ++kk) {
            float4 a0 = *reinterpret_cast<const float4*>(&As[kk][ty * 4]);
            float4 a1 = *reinterpret_cast<const float4*>(&As[kk][ty * 4 + 64]);
            float4 b0 = *reinterpret_cast<const float4*>(&Bs[kk][tx * 4]);
            float4 b1 = *reinterpret_cast<const float4*>(&Bs[kk][tx * 4 + 64]);
            const float ar[2][4] = {{a0.x, a0.y, a0.z, a0.w}, {a1.x, a1.y, a1.z, a1.w}};
            const float br[2][4] = {{b0.x, b0.y, b0.z, b0.w}, {b1.x, b1.y, b1.z, b1.w}};
            #pragma unroll
            for (int i = 0; i < 2; ++i)
                #pragma unroll
                for (int r = 0; r < 4; ++r)
                    #pragma unroll
                    for (int j = 0; j < 2; ++j)
                        #pragma unroll
                        for (int c = 0; c < 4; ++c)
                            acc[i][j][r][c] += ar[i][r] * br[j][c];
        }
    }

    // Epilogue
    #pragma unroll
    for (int i = 0; i < 2; ++i) {
        #pragma unroll
        for (int r = 0; r < 4; ++r) {
            const int row = m0 + i * 64 + ty * 4 + r;
            const float bsv = bias[row];
            #pragma unroll
            for (int j = 0; j < 2; ++j) {
                const int col = n0 + j * 64 + tx * 4;
                float4 v;
                v.x = acc[i][j][r][0] + bsv;
                v.y = acc[i][j][r][1] + bsv;
                v.z = acc[i][j][r][2] + bsv;
                v.w = acc[i][j][r][3] + bsv;
                v.x = v.x > 0.f ? v.x : 0.f;
                v.y = v.y > 0.f ? v.y : 0.f;
                v.z = v.z > 0.f ? v.z : 0.f;
                v.w = v.w > 0.f ? v.w : 0.f;
                const size_t off = (size_t)b * M * NTOT + (size_t)row * NTOT + col;
                if (HAS_RESID) {
                    float4 rv = *reinterpret_cast<const float4*>(&resid[off]);
                    v.x += rv.x; v.y += rv.y; v.z += rv.z; v.w += rv.w;
                }
                *reinterpret_cast<float4*>(&C[off]) = v;
            }
        }
    }
}

// Per-channel sum / sumsq over (B, N) — one block per channel.
__global__ __launch_bounds__(256)
void bn_stats(const float* __restrict__ res, float* __restrict__ stats)
{
    const int c = blockIdx.x;
    const int tid = threadIdx.x;
    float s = 0.f, s2 = 0.f;
    #pragma unroll
    for (int b = 0; b < NB; ++b) {
        const float4* p = reinterpret_cast<const float4*>(res + (size_t)b * COUT * NTOT + (size_t)c * NTOT);
        for (int i = tid; i < NTOT / 4; i += 256) {
            float4 v = p[i];
            s  += v.x + v.y + v.z + v.w;
            s2 += v.x * v.x + v.y * v.y + v.z * v.z + v.w * v.w;
        }
    }
    #pragma unroll
    for (int off = 32; off > 0; off >>= 1) {
        s  += __shfl_down(s, off);
        s2 += __shfl_down(s2, off);
    }
    __shared__ float ls[4], ls2[4];
    const int wave = tid >> 6, lane = tid & 63;
    if (lane == 0) { ls[wave] = s; ls2[wave] = s2; }
    __syncthreads();
    if (tid == 0) {
        float t = 0.f, t2 = 0.f;
        #pragma unroll
        for (int w = 0; w < 4; ++w) { t += ls[w]; t2 += ls2[w]; }
        stats[c] = t;
        stats[COUT + c] = t2;
    }
}

// In-place BN normalize on d_out.
__global__ __launch_bounds__(256)
void bn_norm(float* __restrict__ out, const float* __restrict__ stats,
             const float* __restrict__ gamma, const float* __restrict__ beta)
{
    const int i4 = blockIdx.x * 256 + threadIdx.x;    // float4 index
    const int c = (i4 >> 10) & (COUT - 1);            // 1024 float4 per (b,c)
    const float inv = 1.0f / (NB * NTOT);
    const float mean = stats[c] * inv;
    const float var  = stats[COUT + c] * inv - mean * mean;
    const float sc = gamma[c] * rsqrtf(var + BN_EPS);
    const float sh = beta[c] - mean * sc;
    float4 v = reinterpret_cast<float4*>(out)[i4];
    v.x = v.x * sc + sh;
    v.y = v.y * sc + sh;
    v.z = v.z * sc + sh;
    v.w = v.w * sc + sh;
    reinterpret_cast<float4*>(out)[i4] = v;
}

extern "C" void kernel_launch(void* const* d_in, const int* in_sizes, int n_in,
                              void* d_out, int out_size, void* d_ws, size_t ws_size,
                              hipStream_t stream)
{
    const float* x     = (const float*)d_in[0];
    // d_in[1..4] = Wk, bk, Wq, bq — mathematically dead (softmax rowsum == 1)
    const float* Wv    = (const float*)d_in[5];
    const float* bv    = (const float*)d_in[6];
    const float* Wo    = (const float*)d_in[7];
    const float* bo    = (const float*)d_in[8];
    const float* gamma = (const float*)d_in[9];
    const float* beta  = (const float*)d_in[10];
    float* out = (float*)d_out;

    float* V1    = (float*)d_ws;               // 4*512*4096 fp32 = 33.5 MB
    float* stats = (float*)d_ws;               // reused after V1 is dead (512 floats)

    // k1: V1 = relu(Wv·x + bv)   M=512, K=256
    gemm_fused<CIN, false><<<dim3(NTOT / BN_, FF / BM, NB), 256, 0, stream>>>(
        Wv, x, bv, nullptr, V1, FF);
    // k2: res = x + relu(Wo·V1 + bo) -> d_out   M=256, K=512
    gemm_fused<FF, true><<<dim3(NTOT / BN_, COUT / BM, NB), 256, 0, stream>>>(
        Wo, V1, bo, x, out, COUT);
    // BN batch stats per channel
    bn_stats<<<COUT, 256, 0, stream>>>(out, stats);
    // In-place normalize
    bn_norm<<<(NB * COUT * NTOT / 4) / 256, 256, 0, stream>>>(out, stats, gamma, beta);
}

// Round 3
// 218.508 us; speedup vs baseline: 1.0060x; 1.0060x over previous
//
#include <hip/hip_runtime.h>

// Problem constants
#define NTOT 4096      // T*H*W = 16^3
#define NB   4
#define CIN  256
#define FF   512
#define COUT 256
#define BN_EPS 1e-5f

#define BK  32
#define LDK 40         // padded LDS row stride (elems): 80B = 20 banks -> conflict-free frags

typedef __attribute__((ext_vector_type(8))) short bf16x8;  // 8 bf16 (4 VGPRs)
typedef __attribute__((ext_vector_type(4))) float f32x4;
typedef unsigned short u16;

__device__ __forceinline__ u16 f2bf(float f) {
    unsigned u = __float_as_uint(f);
    u += 0x7fffu + ((u >> 16) & 1u);   // round-to-nearest-even
    return (u16)(u >> 16);
}
__device__ __forceinline__ float bf2f(u16 h) {
    return __uint_as_float(((unsigned)h) << 16);
}

// ---------------------------------------------------------------------------
// Split-bf16 MFMA GEMM.
//   C[b][m][n] = epi( sum_k A[m][k] * B[b][n][k] + bias[m] )
//   A given as hi/lo bf16 planes [M][KDIM]; B as hi/lo planes [b][NTOT][KDIM]
//   (token-major = K-contiguous for both operands).
//   3-term split product: ah*bh + ah*bl + al*bh  ->  ~fp32 accuracy.
// OUT_SPLIT=true : C = relu(.+bias) stored as hi/lo bf16 planes [b][NTOT][M]
//                  (transposed, ready to be the next GEMM's B operand)
// OUT_SPLIT=false: C = resid + relu(.+bias) stored fp32 [b][M][NTOT]
// ---------------------------------------------------------------------------
template<int KDIM, bool OUT_SPLIT>
__global__ __launch_bounds__(256, 2)
void gemm_split(const u16* __restrict__ Ah, const u16* __restrict__ Al,
                const u16* __restrict__ Bh, const u16* __restrict__ Bl,
                const float* __restrict__ bias,
                const float* __restrict__ resid,
                u16* __restrict__ Ch, u16* __restrict__ Cl,
                float* __restrict__ Cf, int M)
{
    __shared__ alignas(16) u16 sAh[128 * LDK];
    __shared__ alignas(16) u16 sAl[128 * LDK];
    __shared__ alignas(16) u16 sBh[128 * LDK];
    __shared__ alignas(16) u16 sBl[128 * LDK];

    const int b   = blockIdx.z;
    const int n0  = blockIdx.x * 128;
    const int m0  = blockIdx.y * 128;
    const int tid = threadIdx.x;
    const int ln  = tid & 63;
    const int wid = tid >> 6;
    const int wm  = wid >> 1, wn = wid & 1;     // 2x2 waves, each 64x64
    const int l15 = ln & 15;
    const int lk8 = (ln >> 4) * 8;              // k-group offset within fragment

    // staging map: thread -> 16B granule (row, gc) and (row+64, gc) per plane
    const int g0r = tid >> 2;
    const int gc  = (tid & 3) * 8;

    const u16* Ahp = Ah + (size_t)(m0 + g0r) * KDIM + gc;
    const u16* Alp = Al + (size_t)(m0 + g0r) * KDIM + gc;
    const u16* Bhp = Bh + ((size_t)b * NTOT + n0 + g0r) * KDIM + gc;
    const u16* Blp = Bl + ((size_t)b * NTOT + n0 + g0r) * KDIM + gc;
    const size_t rowskip = (size_t)64 * KDIM;

    const int wofs0 = g0r * LDK + gc;
    const int wofs1 = (g0r + 64) * LDK + gc;

    f32x4 acc[4][4];
    #pragma unroll
    for (int mt = 0; mt < 4; ++mt)
        #pragma unroll
        for (int nt = 0; nt < 4; ++nt)
            acc[mt][nt] = (f32x4){0.f, 0.f, 0.f, 0.f};

    float4 vA[2][2], vB[2][2];   // [hi/lo][row-half]

#define LOADALL(K0) do {                                        \
        vA[0][0] = *(const float4*)(Ahp + (K0));                \
        vA[0][1] = *(const float4*)(Ahp + rowskip + (K0));      \
        vA[1][0] = *(const float4*)(Alp + (K0));                \
        vA[1][1] = *(const float4*)(Alp + rowskip + (K0));      \
        vB[0][0] = *(const float4*)(Bhp + (K0));                \
        vB[0][1] = *(const float4*)(Bhp + rowskip + (K0));      \
        vB[1][0] = *(const float4*)(Blp + (K0));                \
        vB[1][1] = *(const float4*)(Blp + rowskip + (K0));      \
    } while (0)

#define WRITEALL() do {                                                     \
        *(float4*)&sAh[wofs0] = vA[0][0]; *(float4*)&sAh[wofs1] = vA[0][1]; \
        *(float4*)&sAl[wofs0] = vA[1][0]; *(float4*)&sAl[wofs1] = vA[1][1]; \
        *(float4*)&sBh[wofs0] = vB[0][0]; *(float4*)&sBh[wofs1] = vB[0][1]; \
        *(float4*)&sBl[wofs0] = vB[1][0]; *(float4*)&sBl[wofs1] = vB[1][1]; \
    } while (0)

    const int aro = (wm * 64 + l15) * LDK + lk8;
    const int bro = (wn * 64 + l15) * LDK + lk8;

    LOADALL(0);
    constexpr int NSTEP = KDIM / BK;
    for (int t = 0; t < NSTEP; ++t) {
        __syncthreads();             // previous step's LDS reads complete
        WRITEALL();                  // (implicit vmcnt wait on staged regs)
        __syncthreads();             // tile visible to all waves
        if (t + 1 < NSTEP) LOADALL((t + 1) * BK);   // prefetch overlaps MFMA

        bf16x8 aH[4], aL[4], bH[4], bL[4];
        #pragma unroll
        for (int mt = 0; mt < 4; ++mt) {
            aH[mt] = *(const bf16x8*)&sAh[aro + mt * 16 * LDK];
            aL[mt] = *(const bf16x8*)&sAl[aro + mt * 16 * LDK];
        }
        #pragma unroll
        for (int nt = 0; nt < 4; ++nt) {
            bH[nt] = *(const bf16x8*)&sBh[bro + nt * 16 * LDK];
            bL[nt] = *(const bf16x8*)&sBl[bro + nt * 16 * LDK];
        }
        #pragma unroll
        for (int mt = 0; mt < 4; ++mt)
            #pragma unroll
            for (int nt = 0; nt < 4; ++nt) {
                acc[mt][nt] = __builtin_amdgcn_mfma_f32_16x16x32_bf16(aH[mt], bH[nt], acc[mt][nt], 0, 0, 0);
                acc[mt][nt] = __builtin_amdgcn_mfma_f32_16x16x32_bf16(aH[mt], bL[nt], acc[mt][nt], 0, 0, 0);
                acc[mt][nt] = __builtin_amdgcn_mfma_f32_16x16x32_bf16(aL[mt], bH[nt], acc[mt][nt], 0, 0, 0);
            }
    }
#undef LOADALL
#undef WRITEALL

    // Epilogue. C/D frag: col = ln&15, row = (ln>>4)*4 + r  [m89 verified]
    const int lkr = (ln >> 4) * 4;
    if (OUT_SPLIT) {
        #pragma unroll
        for (int mt = 0; mt < 4; ++mt) {
            const int fbase = m0 + wm * 64 + mt * 16 + lkr;
            const float4 bia = *(const float4*)&bias[fbase];
            const float bb[4] = {bia.x, bia.y, bia.z, bia.w};
            #pragma unroll
            for (int nt = 0; nt < 4; ++nt) {
                const int n = n0 + wn * 64 + nt * 16 + l15;
                float v[4]; u16 h[4], l[4];
                #pragma unroll
                for (int r = 0; r < 4; ++r) {
                    v[r] = fmaxf(acc[mt][nt][r] + bb[r], 0.f);
                    h[r] = f2bf(v[r]);
                    l[r] = f2bf(v[r] - bf2f(h[r]));
                }
                const size_t off = ((size_t)b * NTOT + n) * M + fbase;
                ushort4 hv = {h[0], h[1], h[2], h[3]};
                ushort4 lv = {l[0], l[1], l[2], l[3]};
                *(ushort4*)&Ch[off] = hv;
                *(ushort4*)&Cl[off] = lv;
            }
        }
    } else {
        #pragma unroll
        for (int mt = 0; mt < 4; ++mt) {
            const int fbase = m0 + wm * 64 + mt * 16 + lkr;
            const float4 bia = *(const float4*)&bias[fbase];
            const float bb[4] = {bia.x, bia.y, bia.z, bia.w};
            #pragma unroll
            for (int nt = 0; nt < 4; ++nt) {
                const int n = n0 + wn * 64 + nt * 16 + l15;
                #pragma unroll
                for (int r = 0; r < 4; ++r) {
                    const size_t off = ((size_t)b * M + fbase + r) * NTOT + n;
                    Cf[off] = fmaxf(acc[mt][nt][r] + bb[r], 0.f) + resid[off];
                }
            }
        }
    }
}

// ---------------------------------------------------------------------------
// x [b][c][n] fp32  ->  xT hi/lo bf16 planes [b][n][c]  (transpose + split)
// ---------------------------------------------------------------------------
__global__ __launch_bounds__(256)
void transpose_split(const float* __restrict__ x,
                     u16* __restrict__ xTh, u16* __restrict__ xTl)
{
    __shared__ float t[64][65];
    const int b = blockIdx.z, n0 = blockIdx.x * 64, c0 = blockIdx.y * 64;
    const int tid = threadIdx.x, tx = tid & 15, ty = tid >> 4;
    #pragma unroll
    for (int p = 0; p < 4; ++p) {
        const int c = ty + 16 * p;
        float4 v = *(const float4*)&x[((size_t)b * CIN + c0 + c) * NTOT + n0 + tx * 4];
        t[c][tx * 4 + 0] = v.x; t[c][tx * 4 + 1] = v.y;
        t[c][tx * 4 + 2] = v.z; t[c][tx * 4 + 3] = v.w;
    }
    __syncthreads();
    #pragma unroll
    for (int p = 0; p < 4; ++p) {
        const int n = ty + 16 * p;
        float f[4]; u16 h[4], l[4];
        #pragma unroll
        for (int q = 0; q < 4; ++q) {
            f[q] = t[tx * 4 + q][n];
            h[q] = f2bf(f[q]);
            l[q] = f2bf(f[q] - bf2f(h[q]));
        }
        const size_t off = ((size_t)b * NTOT + n0 + n) * CIN + c0 + tx * 4;
        ushort4 hv = {h[0], h[1], h[2], h[3]};
        ushort4 lv = {l[0], l[1], l[2], l[3]};
        *(ushort4*)&xTh[off] = hv;
        *(ushort4*)&xTl[off] = lv;
    }
}

// Weights -> hi/lo bf16 planes (no transpose; both already K-contiguous).
__global__ __launch_bounds__(256)
void wconvert(const float* __restrict__ Wv, const float* __restrict__ Wo,
              u16* __restrict__ Wvh, u16* __restrict__ Wvl,
              u16* __restrict__ Woh, u16* __restrict__ Wol)
{
    const int blk = blockIdx.x;
    const float* src; u16 *dh, *dl;
    int base;
    if (blk < 128) { src = Wv; dh = Wvh; dl = Wvl; base = blk * 1024; }
    else           { src = Wo; dh = Woh; dl = Wol; base = (blk - 128) * 1024; }
    const int i = base + threadIdx.x * 4;
    float4 v = *(const float4*)&src[i];
    const float f[4] = {v.x, v.y, v.z, v.w};
    u16 h[4], l[4];
    #pragma unroll
    for (int q = 0; q < 4; ++q) {
        h[q] = f2bf(f[q]);
        l[q] = f2bf(f[q] - bf2f(h[q]));
    }
    ushort4 hv = {h[0], h[1], h[2], h[3]};
    ushort4 lv = {l[0], l[1], l[2], l[3]};
    *(ushort4*)&dh[i] = hv;
    *(ushort4*)&dl[i] = lv;
}

// Per-channel sum / sumsq over (B, N) — one block per channel.
__global__ __launch_bounds__(256)
void bn_stats(const float* __restrict__ res, float* __restrict__ stats)
{
    const int c = blockIdx.x;
    const int tid = threadIdx.x;
    float s = 0.f, s2 = 0.f;
    #pragma unroll
    for (int b = 0; b < NB; ++b) {
        const float4* p = reinterpret_cast<const float4*>(res + (size_t)b * COUT * NTOT + (size_t)c * NTOT);
        for (int i = tid; i < NTOT / 4; i += 256) {
            float4 v = p[i];
            s  += v.x + v.y + v.z + v.w;
            s2 += v.x * v.x + v.y * v.y + v.z * v.z + v.w * v.w;
        }
    }
    #pragma unroll
    for (int off = 32; off > 0; off >>= 1) {
        s  += __shfl_down(s, off);
        s2 += __shfl_down(s2, off);
    }
    __shared__ float ls[4], ls2[4];
    const int wave = tid >> 6, lane = tid & 63;
    if (lane == 0) { ls[wave] = s; ls2[wave] = s2; }
    __syncthreads();
    if (tid == 0) {
        float t = 0.f, t2 = 0.f;
        #pragma unroll
        for (int w = 0; w < 4; ++w) { t += ls[w]; t2 += ls2[w]; }
        stats[c] = t;
        stats[COUT + c] = t2;
    }
}

__global__ __launch_bounds__(256)
void bn_norm(float* __restrict__ out, const float* __restrict__ stats,
             const float* __restrict__ gamma, const float* __restrict__ beta)
{
    const int i4 = blockIdx.x * 256 + threadIdx.x;
    const int c = (i4 >> 10) & (COUT - 1);
    const float inv = 1.0f / (NB * NTOT);
    const float mean = stats[c] * inv;
    const float var  = stats[COUT + c] * inv - mean * mean;
    const float sc = gamma[c] * rsqrtf(var + BN_EPS);
    const float sh = beta[c] - mean * sc;
    float4 v = reinterpret_cast<float4*>(out)[i4];
    v.x = v.x * sc + sh;
    v.y = v.y * sc + sh;
    v.z = v.z * sc + sh;
    v.w = v.w * sc + sh;
    reinterpret_cast<float4*>(out)[i4] = v;
}

extern "C" void kernel_launch(void* const* d_in, const int* in_sizes, int n_in,
                              void* d_out, int out_size, void* d_ws, size_t ws_size,
                              hipStream_t stream)
{
    const float* x     = (const float*)d_in[0];
    // d_in[1..4] = Wk, bk, Wq, bq — dead (softmax rowsum == 1)
    const float* Wv    = (const float*)d_in[5];
    const float* bv    = (const float*)d_in[6];
    const float* Wo    = (const float*)d_in[7];
    const float* bo    = (const float*)d_in[8];
    const float* gamma = (const float*)d_in[9];
    const float* beta  = (const float*)d_in[10];
    float* out = (float*)d_out;

    // workspace layout (elem counts; ~51.4 MB total)
    u16* xTh  = (u16*)d_ws;
    u16* xTl  = xTh  + (size_t)NB * NTOT * CIN;
    u16* V1Th = xTl  + (size_t)NB * NTOT * CIN;
    u16* V1Tl = V1Th + (size_t)NB * NTOT * FF;
    u16* Wvh  = V1Tl + (size_t)NB * NTOT * FF;
    u16* Wvl  = Wvh  + (size_t)FF * CIN;
    u16* Woh  = Wvl  + (size_t)FF * CIN;
    u16* Wol  = Woh  + (size_t)COUT * FF;
    float* stats = (float*)(Wol + (size_t)COUT * FF);

    wconvert<<<dim3(256), 256, 0, stream>>>(Wv, Wo, Wvh, Wvl, Woh, Wol);
    transpose_split<<<dim3(NTOT / 64, CIN / 64, NB), 256, 0, stream>>>(x, xTh, xTl);

    // k1: V1T = relu(Wv·x + bv)^T  (split bf16, token-major)   M=512, K=256
    gemm_split<CIN, true><<<dim3(NTOT / 128, FF / 128, NB), 256, 0, stream>>>(
        Wvh, Wvl, xTh, xTl, bv, nullptr, V1Th, V1Tl, nullptr, FF);
    // k2: out = x + relu(Wo·V1 + bo)  (fp32)                   M=256, K=512
    gemm_split<FF, false><<<dim3(NTOT / 128, COUT / 128, NB), 256, 0, stream>>>(
        Woh, Wol, V1Th, V1Tl, bo, x, nullptr, nullptr, out, COUT);

    bn_stats<<<COUT, 256, 0, stream>>>(out, stats);
    bn_norm<<<(NB * COUT * NTOT / 4) / 256, 256, 0, stream>>>(out, stats, gamma, beta);
}

// Round 8
// 197.259 us; speedup vs baseline: 1.1143x; 1.1077x over previous
//
#include <hip/hip_runtime.h>

// Problem constants
#define NTOT 4096      // T*H*W = 16^3
#define NB   4
#define CIN  256
#define FF   512
#define COUT 256
#define BN_EPS 1e-5f
#define NT_B 64        // tokens per fused block

typedef __attribute__((ext_vector_type(8))) short bf16x8;  // 8 bf16 = 16 B
typedef __attribute__((ext_vector_type(4))) float f32x4;
typedef unsigned short u16;

__device__ __forceinline__ u16 f2bf(float f) {
    unsigned u = __float_as_uint(f);
    u += 0x7fffu + ((u >> 16) & 1u);   // round-to-nearest-even
    return (u16)(u >> 16);
}
__device__ __forceinline__ float bf2f(u16 h) {
    return __uint_as_float(((unsigned)h) << 16);
}

// ---------------------------------------------------------------------------
// Weights -> packed split-bf16 granule layout + zero BN stats.
// Packed layout (per plane): granule g = ((m>>4)*NKG + kg)*16 + (m&15),
// elems g*8+j hold W[m][kg*8+j].  A-fragment read for m-tile mt, k-step ks:
// lane ln reads granule ((mt)*NKG + ks*4 + (ln>>4))*16 + (ln&15)  -> 16B/lane,
// lanes contiguous. 32768 granules total (Wv 16384 + Wo 16384).
// ---------------------------------------------------------------------------
__global__ __launch_bounds__(256)
void prep_weights(const float* __restrict__ Wv, const float* __restrict__ Wo,
                  u16* __restrict__ Wvh, u16* __restrict__ Wvl,
                  u16* __restrict__ Woh, u16* __restrict__ Wol,
                  float* __restrict__ stats)
{
    const int t = threadIdx.x;
    const int g = blockIdx.x * 256 + t;
    if (blockIdx.x == 0) { stats[t] = 0.f; stats[256 + t] = 0.f; }

    const float* src; u16 *dh, *dl; int m, kg, K;
    if (g < 16384) { m = g >> 5;           kg = g & 31; K = CIN; src = Wv; dh = Wvh; dl = Wvl; }
    else           { int g2 = g - 16384; m = g2 >> 6; kg = g2 & 63; K = FF;  src = Wo; dh = Woh; dl = Wol; }

    const int nkg = K >> 3;
    const size_t gran = ((size_t)(m >> 4) * nkg + kg) * 16 + (m & 15);
    float4 v0 = *(const float4*)&src[(size_t)m * K + kg * 8];
    float4 v1 = *(const float4*)&src[(size_t)m * K + kg * 8 + 4];
    const float f[8] = {v0.x, v0.y, v0.z, v0.w, v1.x, v1.y, v1.z, v1.w};
    u16 h[8], l[8];
    #pragma unroll
    for (int j = 0; j < 8; ++j) { h[j] = f2bf(f[j]); l[j] = f2bf(f[j] - bf2f(h[j])); }
    bf16x8 hv = {(short)h[0],(short)h[1],(short)h[2],(short)h[3],(short)h[4],(short)h[5],(short)h[6],(short)h[7]};
    bf16x8 lv = {(short)l[0],(short)l[1],(short)l[2],(short)l[3],(short)l[4],(short)l[5],(short)l[6],(short)l[7]};
    *(bf16x8*)&dh[gran * 8] = hv;
    *(bf16x8*)&dl[gran * 8] = lv;
}

// ---------------------------------------------------------------------------
// x [b][c][n] fp32 -> packed split planes, per (b, token-block):
//   xh[((b*64+tb)*32 + kg)*64*8 + tok*8 + j] = bf16_hi(x[b][kg*8+j][tb*64+tok])
// All global writes are contiguous 16 B/lane granules (no scatter).
// ---------------------------------------------------------------------------
__global__ __launch_bounds__(256)
void pack_x(const float* __restrict__ x, u16* __restrict__ xh, u16* __restrict__ xl)
{
    __shared__ float xt[CIN][NT_B + 4];   // 256 x 68 f32 (~70 KB, 2 blocks/CU)
    const int t = threadIdx.x;
    const int b = blockIdx.x >> 6, tb = blockIdx.x & 63;
    const int n0 = tb * NT_B;
    const int c16 = t >> 4, tok4 = (t & 15) * 4;

    #pragma unroll
    for (int rr = 0; rr < 16; ++rr) {
        const int c = rr * 16 + c16;
        float4 v = *(const float4*)&x[((size_t)b * CIN + c) * NTOT + n0 + tok4];
        *(float4*)&xt[c][tok4] = v;       // row stride 272 B = 17*16 -> aligned
    }
    __syncthreads();

    const int tok = t & 63, wq = t >> 6;
    #pragma unroll
    for (int r = 0; r < 8; ++r) {
        const int kg = r * 4 + wq;
        u16 h8[8], l8[8];
        #pragma unroll
        for (int j = 0; j < 8; ++j) {
            float f = xt[kg * 8 + j][tok];
            h8[j] = f2bf(f);
            l8[j] = f2bf(f - bf2f(h8[j]));
        }
        const size_t e = ((((size_t)(b * 64 + tb)) * 32 + kg) * 64 + tok) * 8;
        bf16x8 hv = {(short)h8[0],(short)h8[1],(short)h8[2],(short)h8[3],(short)h8[4],(short)h8[5],(short)h8[6],(short)h8[7]};
        bf16x8 lv = {(short)l8[0],(short)l8[1],(short)l8[2],(short)l8[3],(short)l8[4],(short)l8[5],(short)l8[6],(short)l8[7]};
        *(bf16x8*)&xh[e] = hv;
        *(bf16x8*)&xl[e] = lv;
    }
}

// ---------------------------------------------------------------------------
// Fused: h = relu(Wv x + bv); y = relu(Wo h + bo) + x; BN partial sums.
// One block = 64 tokens, 4 waves, 128 KB LDS, 1 block/CU, grid=256.
// h never touches HBM. Split-bf16 3-term MFMA throughout.
// ---------------------------------------------------------------------------
__global__ __launch_bounds__(256, 1)
void fused_mlp(const u16* __restrict__ xh, const u16* __restrict__ xl,
               const u16* __restrict__ Wvh, const u16* __restrict__ Wvl,
               const u16* __restrict__ Woh, const u16* __restrict__ Wol,
               const float* __restrict__ bv, const float* __restrict__ bo,
               const float* __restrict__ x, float* __restrict__ out,
               float* __restrict__ stats)
{
    __shared__ __align__(16) unsigned char smem[131072];
    u16*   xsh = (u16*)smem;               // 32 KB  (phase A)
    u16*   xsl = (u16*)(smem + 32768);     // 32 KB
    u16*   hsh = (u16*)smem;               // 64 KB  (phase B, overwrites xs)
    u16*   hsl = (u16*)(smem + 65536);     // 64 KB
    float* os  = (float*)smem;             // 256 x 68 f32 (phase C)

    const int t  = threadIdx.x;
    const int b  = blockIdx.x >> 6, tb = blockIdx.x & 63;
    const int n0 = tb * NT_B;
    const int ln = t & 63, w = t >> 6;
    const int l15 = ln & 15, hi = ln >> 4;

    // ---- stage x tiles (linear 64 KB copy, 16 B/lane contiguous) ----
    const size_t xbase = ((size_t)(b * 64 + tb)) * 16384;   // u16 per plane-block
    #pragma unroll
    for (int i = 0; i < 8; ++i) {
        const int e = (i * 256 + t) * 8;
        *(bf16x8*)&xsh[e] = *(const bf16x8*)&xh[xbase + e];
        *(bf16x8*)&xsl[e] = *(const bf16x8*)&xl[xbase + e];
    }
    __syncthreads();

    // ---- GEMM1: h[512][64] = Wv * x, K=256 (8 k-steps) ----
    f32x4 acc1[8][4];
    #pragma unroll
    for (int mt = 0; mt < 8; ++mt)
        #pragma unroll
        for (int nt = 0; nt < 4; ++nt)
            acc1[mt][nt] = (f32x4){0.f, 0.f, 0.f, 0.f};

    #pragma unroll 2
    for (int ks = 0; ks < 8; ++ks) {
        bf16x8 bh[4], bl[4];
        #pragma unroll
        for (int nt = 0; nt < 4; ++nt) {
            const int g = (ks * 4 + hi) * 64 + nt * 16 + l15;
            bh[nt] = *(const bf16x8*)&xsh[g * 8];
            bl[nt] = *(const bf16x8*)&xsl[g * 8];
        }
        #pragma unroll
        for (int mt = 0; mt < 8; ++mt) {
            const size_t g = ((size_t)(w * 8 + mt) * 32 + ks * 4 + hi) * 16 + l15;
            bf16x8 ah = *(const bf16x8*)&Wvh[g * 8];
            bf16x8 al = *(const bf16x8*)&Wvl[g * 8];
            #pragma unroll
            for (int nt = 0; nt < 4; ++nt) {
                acc1[mt][nt] = __builtin_amdgcn_mfma_f32_16x16x32_bf16(ah, bh[nt], acc1[mt][nt], 0, 0, 0);
                acc1[mt][nt] = __builtin_amdgcn_mfma_f32_16x16x32_bf16(ah, bl[nt], acc1[mt][nt], 0, 0, 0);
                acc1[mt][nt] = __builtin_amdgcn_mfma_f32_16x16x32_bf16(al, bh[nt], acc1[mt][nt], 0, 0, 0);
            }
        }
    }
    __syncthreads();   // xs reads complete before hs overwrite

    // ---- h epilogue: relu(acc1 + bv) -> split bf16 -> LDS (hs) ----
    // C/D frag: col = l15 (token), row-in-tile = hi*4 + r  [m89 verified]
    #pragma unroll
    for (int mt = 0; mt < 8; ++mt) {
        const int ff0 = w * 128 + mt * 16 + hi * 4;
        float4 bia = *(const float4*)&bv[ff0];
        const float bb[4] = {bia.x, bia.y, bia.z, bia.w};
        const int kg = ff0 >> 3;
        const int jo = (hi & 1) * 4;
        #pragma unroll
        for (int nt = 0; nt < 4; ++nt) {
            const int tok = nt * 16 + l15;
            u16 hh[4], hl[4];
            #pragma unroll
            for (int r = 0; r < 4; ++r) {
                float v = fmaxf(acc1[mt][nt][r] + bb[r], 0.f);
                hh[r] = f2bf(v);
                hl[r] = f2bf(v - bf2f(hh[r]));
            }
            const int e = (kg * 64 + tok) * 8 + jo;
            *(ushort4*)&hsh[e] = (ushort4){hh[0], hh[1], hh[2], hh[3]};
            *(ushort4*)&hsl[e] = (ushort4){hl[0], hl[1], hl[2], hl[3]};
        }
    }
    __syncthreads();

    // ---- GEMM2: y[256][64] = Wo * h, K=512 (16 k-steps) ----
    f32x4 acc2[4][4];
    #pragma unroll
    for (int mt = 0; mt < 4; ++mt)
        #pragma unroll
        for (int nt = 0; nt < 4; ++nt)
            acc2[mt][nt] = (f32x4){0.f, 0.f, 0.f, 0.f};

    #pragma unroll 2
    for (int ks = 0; ks < 16; ++ks) {
        bf16x8 bh[4], bl[4];
        #pragma unroll
        for (int nt = 0; nt < 4; ++nt) {
            const int g = (ks * 4 + hi) * 64 + nt * 16 + l15;
            bh[nt] = *(const bf16x8*)&hsh[g * 8];
            bl[nt] = *(const bf16x8*)&hsl[g * 8];
        }
        #pragma unroll
        for (int mt = 0; mt < 4; ++mt) {
            const size_t g = ((size_t)(w * 4 + mt) * 64 + ks * 4 + hi) * 16 + l15;
            bf16x8 ah = *(const bf16x8*)&Woh[g * 8];
            bf16x8 al = *(const bf16x8*)&Wol[g * 8];
            #pragma unroll
            for (int nt = 0; nt < 4; ++nt) {
                acc2[mt][nt] = __builtin_amdgcn_mfma_f32_16x16x32_bf16(ah, bh[nt], acc2[mt][nt], 0, 0, 0);
                acc2[mt][nt] = __builtin_amdgcn_mfma_f32_16x16x32_bf16(ah, bl[nt], acc2[mt][nt], 0, 0, 0);
                acc2[mt][nt] = __builtin_amdgcn_mfma_f32_16x16x32_bf16(al, bh[nt], acc2[mt][nt], 0, 0, 0);
            }
        }
    }
    __syncthreads();   // hs reads complete before os overwrite

    // ---- out epilogue: relu(acc2 + bo) -> os (LDS transpose) ----
    #pragma unroll
    for (int mt = 0; mt < 4; ++mt) {
        const int ch0 = w * 64 + mt * 16 + hi * 4;
        float4 bia = *(const float4*)&bo[ch0];
        const float bb[4] = {bia.x, bia.y, bia.z, bia.w};
        #pragma unroll
        for (int nt = 0; nt < 4; ++nt) {
            const int tok = nt * 16 + l15;
            #pragma unroll
            for (int r = 0; r < 4; ++r)
                os[(ch0 + r) * 68 + tok] = fmaxf(acc2[mt][nt][r] + bb[r], 0.f);
        }
    }
    __syncthreads();

    // ---- final: out = os + x (coalesced float4), BN partial sums ----
    const int chq = t >> 4, tok4 = (t & 15) * 4;
    #pragma unroll
    for (int ii = 0; ii < 16; ++ii) {
        const int ch = chq + ii * 16;
        float4 o = *(float4*)&os[ch * 68 + tok4];
        const size_t goff = ((size_t)b * COUT + ch) * NTOT + n0 + tok4;
        float4 rx = *(const float4*)&x[goff];
        float4 v = {o.x + rx.x, o.y + rx.y, o.z + rx.z, o.w + rx.w};
        *(float4*)&out[goff] = v;
        float s  = v.x + v.y + v.z + v.w;
        float s2 = v.x * v.x + v.y * v.y + v.z * v.z + v.w * v.w;
        #pragma unroll
        for (int off = 1; off < 16; off <<= 1) {
            s  += __shfl_xor(s, off);
            s2 += __shfl_xor(s2, off);
        }
        if (l15 == 0) {
            atomicAdd(&stats[ch], s);
            atomicAdd(&stats[COUT + ch], s2);
        }
    }
}

// ---------------------------------------------------------------------------
// BN normalize (stats = per-channel sum / sumsq over B*N).
// ---------------------------------------------------------------------------
__global__ __launch_bounds__(256)
void bn_norm(float* __restrict__ out, const float* __restrict__ stats,
             const float* __restrict__ gamma, const float* __restrict__ beta)
{
    const int i4 = blockIdx.x * 256 + threadIdx.x;
    const int c = (i4 >> 10) & (COUT - 1);
    const float inv = 1.0f / (NB * NTOT);
    const float mean = stats[c] * inv;
    const float var  = stats[COUT + c] * inv - mean * mean;
    const float sc = gamma[c] * rsqrtf(var + BN_EPS);
    const float sh = beta[c] - mean * sc;
    float4 v = reinterpret_cast<float4*>(out)[i4];
    v.x = v.x * sc + sh;
    v.y = v.y * sc + sh;
    v.z = v.z * sc + sh;
    v.w = v.w * sc + sh;
    reinterpret_cast<float4*>(out)[i4] = v;
}

extern "C" void kernel_launch(void* const* d_in, const int* in_sizes, int n_in,
                              void* d_out, int out_size, void* d_ws, size_t ws_size,
                              hipStream_t stream)
{
    const float* x     = (const float*)d_in[0];
    // d_in[1..4] = Wk, bk, Wq, bq — dead (softmax rowsum == 1)
    const float* Wv    = (const float*)d_in[5];
    const float* bv    = (const float*)d_in[6];
    const float* Wo    = (const float*)d_in[7];
    const float* bo    = (const float*)d_in[8];
    const float* gamma = (const float*)d_in[9];
    const float* beta  = (const float*)d_in[10];
    float* out = (float*)d_out;

    // workspace layout (~17.8 MB)
    u16* xh   = (u16*)d_ws;
    u16* xl   = xh  + (size_t)NB * NTOT * CIN;
    u16* Wvh  = xl  + (size_t)NB * NTOT * CIN;
    u16* Wvl  = Wvh + (size_t)FF * CIN;
    u16* Woh  = Wvl + (size_t)FF * CIN;
    u16* Wol  = Woh + (size_t)COUT * FF;
    float* stats = (float*)(Wol + (size_t)COUT * FF);

    prep_weights<<<128, 256, 0, stream>>>(Wv, Wo, Wvh, Wvl, Woh, Wol, stats);
    pack_x<<<NB * 64, 256, 0, stream>>>(x, xh, xl);
    fused_mlp<<<NB * 64, 256, 0, stream>>>(xh, xl, Wvh, Wvl, Woh, Wol,
                                           bv, bo, x, out, stats);
    bn_norm<<<(NB * COUT * NTOT / 4) / 256, 256, 0, stream>>>(out, stats, gamma, beta);
}

// Round 9
// 160.224 us; speedup vs baseline: 1.3719x; 1.2311x over previous
//
#include <hip/hip_runtime.h>

// Problem constants
#define NTOT 4096      // T*H*W = 16^3
#define NB   4
#define CIN  256
#define FF   512
#define COUT 256
#define BN_EPS 1e-5f
#define NT_B 32        // tokens per fused block (was 64)
#define OSP  36        // padded out-stage row stride (f32)

typedef __attribute__((ext_vector_type(8))) short bf16x8;  // 8 bf16 = 16 B
typedef __attribute__((ext_vector_type(4))) float f32x4;
typedef unsigned short u16;

__device__ __forceinline__ u16 f2bf(float f) {
    unsigned u = __float_as_uint(f);
    u += 0x7fffu + ((u >> 16) & 1u);   // round-to-nearest-even
    return (u16)(u >> 16);
}
__device__ __forceinline__ float bf2f(u16 h) {
    return __uint_as_float(((unsigned)h) << 16);
}

// ---------------------------------------------------------------------------
// Weights -> packed split-bf16 granule layout + zero BN stats.
// Granule g = ((m>>4)*NKG + kg)*16 + (m&15); elems g*8+j = W[m][kg*8+j].
// ---------------------------------------------------------------------------
__global__ __launch_bounds__(256)
void prep_weights(const float* __restrict__ Wv, const float* __restrict__ Wo,
                  u16* __restrict__ Wvh, u16* __restrict__ Wvl,
                  u16* __restrict__ Woh, u16* __restrict__ Wol,
                  float* __restrict__ stats)
{
    const int t = threadIdx.x;
    const int g = blockIdx.x * 256 + t;
    if (blockIdx.x == 0) { stats[t] = 0.f; stats[256 + t] = 0.f; }

    const float* src; u16 *dh, *dl; int m, kg, K;
    if (g < 16384) { m = g >> 5;           kg = g & 31; K = CIN; src = Wv; dh = Wvh; dl = Wvl; }
    else           { int g2 = g - 16384; m = g2 >> 6; kg = g2 & 63; K = FF;  src = Wo; dh = Woh; dl = Wol; }

    const int nkg = K >> 3;
    const size_t gran = ((size_t)(m >> 4) * nkg + kg) * 16 + (m & 15);
    float4 v0 = *(const float4*)&src[(size_t)m * K + kg * 8];
    float4 v1 = *(const float4*)&src[(size_t)m * K + kg * 8 + 4];
    const float f[8] = {v0.x, v0.y, v0.z, v0.w, v1.x, v1.y, v1.z, v1.w};
    u16 h[8], l[8];
    #pragma unroll
    for (int j = 0; j < 8; ++j) { h[j] = f2bf(f[j]); l[j] = f2bf(f[j] - bf2f(h[j])); }
    bf16x8 hv = {(short)h[0],(short)h[1],(short)h[2],(short)h[3],(short)h[4],(short)h[5],(short)h[6],(short)h[7]};
    bf16x8 lv = {(short)l[0],(short)l[1],(short)l[2],(short)l[3],(short)l[4],(short)l[5],(short)l[6],(short)l[7]};
    *(bf16x8*)&dh[gran * 8] = hv;
    *(bf16x8*)&dl[gran * 8] = lv;
}

// ---------------------------------------------------------------------------
// x [b][c][n] fp32 -> packed split planes in 32-token sub-blocks:
//   e = (((b*128 + tb2)*32 + kg)*32 + tok32)*8 ; elem j = x[b][kg*8+j][tb2*32+tok32]
// All global writes contiguous 16 B/lane granules.
// ---------------------------------------------------------------------------
__global__ __launch_bounds__(256)
void pack_x(const float* __restrict__ x, u16* __restrict__ xh, u16* __restrict__ xl)
{
    __shared__ float xt[CIN][68];   // 64 tokens + pad
    const int t = threadIdx.x;
    const int b = blockIdx.x >> 6, tb = blockIdx.x & 63;
    const int n0 = tb * 64;
    const int c16 = t >> 4, tok4 = (t & 15) * 4;

    #pragma unroll
    for (int rr = 0; rr < 16; ++rr) {
        const int c = rr * 16 + c16;
        float4 v = *(const float4*)&x[((size_t)b * CIN + c) * NTOT + n0 + tok4];
        *(float4*)&xt[c][tok4] = v;
    }
    __syncthreads();

    const int tok = t & 63, wq = t >> 6;
    const int sb = tok >> 5, tok32 = tok & 31;
    #pragma unroll
    for (int r = 0; r < 8; ++r) {
        const int kg = r * 4 + wq;
        u16 h8[8], l8[8];
        #pragma unroll
        for (int j = 0; j < 8; ++j) {
            float f = xt[kg * 8 + j][tok];
            h8[j] = f2bf(f);
            l8[j] = f2bf(f - bf2f(h8[j]));
        }
        const size_t e = ((((size_t)(b * 128 + tb * 2 + sb)) * 32 + kg) * 32 + tok32) * 8;
        bf16x8 hv = {(short)h8[0],(short)h8[1],(short)h8[2],(short)h8[3],(short)h8[4],(short)h8[5],(short)h8[6],(short)h8[7]};
        bf16x8 lv = {(short)l8[0],(short)l8[1],(short)l8[2],(short)l8[3],(short)l8[4],(short)l8[5],(short)l8[6],(short)l8[7]};
        *(bf16x8*)&xh[e] = hv;
        *(bf16x8*)&xl[e] = lv;
    }
}

// ---------------------------------------------------------------------------
// Fused MLP: 32 tokens/block, 8 waves (512 thr), 64 KB LDS -> 2 blocks/CU,
// 16 waves/CU (4/SIMD). h stays in LDS. Split-bf16 3-term MFMA.
// ---------------------------------------------------------------------------
__global__ __launch_bounds__(512, 4)
void fused_mlp(const u16* __restrict__ xh, const u16* __restrict__ xl,
               const u16* __restrict__ Wvh, const u16* __restrict__ Wvl,
               const u16* __restrict__ Woh, const u16* __restrict__ Wol,
               const float* __restrict__ bv, const float* __restrict__ bo,
               const float* __restrict__ x, float* __restrict__ out,
               float* __restrict__ stats)
{
    __shared__ __align__(16) unsigned char smem[65536];
    u16*   xsh = (u16*)smem;               // 16 KB  (phase A)
    u16*   xsl = (u16*)(smem + 16384);     // 16 KB
    u16*   hsh = (u16*)smem;               // 32 KB  (phase B, overwrites xs)
    u16*   hsl = (u16*)(smem + 32768);     // 32 KB
    float* os  = (float*)smem;             // 256 x OSP f32 = 36 KB (phase C)

    const int t   = threadIdx.x;
    const int b   = blockIdx.x >> 7;        // 128 token-blocks per batch
    const int tb2 = blockIdx.x & 127;
    const int n0  = tb2 * NT_B;
    const int ln  = t & 63, w = t >> 6;     // 8 waves
    const int l15 = ln & 15, hi = ln >> 4;

    // ---- stage x tile (32 KB linear copy, 16 B/lane) ----
    const size_t xbase = ((size_t)(b * 128 + tb2)) * 8192;   // u16 per plane-block
    #pragma unroll
    for (int i = 0; i < 2; ++i) {
        const int e = (i * 512 + t) * 8;
        *(bf16x8*)&xsh[e] = *(const bf16x8*)&xh[xbase + e];
        *(bf16x8*)&xsl[e] = *(const bf16x8*)&xl[xbase + e];
    }
    __syncthreads();

    // ---- GEMM1: h[512][32] = Wv * x, K=256 (8 k-steps); wave w: rows w*64.. ----
    f32x4 acc1[4][2];
    #pragma unroll
    for (int mt = 0; mt < 4; ++mt)
        #pragma unroll
        for (int nt = 0; nt < 2; ++nt)
            acc1[mt][nt] = (f32x4){0.f, 0.f, 0.f, 0.f};

    #pragma unroll 2
    for (int ks = 0; ks < 8; ++ks) {
        bf16x8 bh[2], bl[2];
        #pragma unroll
        for (int nt = 0; nt < 2; ++nt) {
            const int g = (ks * 4 + hi) * 32 + nt * 16 + l15;
            bh[nt] = *(const bf16x8*)&xsh[g * 8];
            bl[nt] = *(const bf16x8*)&xsl[g * 8];
        }
        #pragma unroll
        for (int mt = 0; mt < 4; ++mt) {
            const size_t g = ((size_t)(w * 4 + mt) * 32 + ks * 4 + hi) * 16 + l15;
            bf16x8 ah = *(const bf16x8*)&Wvh[g * 8];
            bf16x8 al = *(const bf16x8*)&Wvl[g * 8];
            #pragma unroll
            for (int nt = 0; nt < 2; ++nt) {
                acc1[mt][nt] = __builtin_amdgcn_mfma_f32_16x16x32_bf16(ah, bh[nt], acc1[mt][nt], 0, 0, 0);
                acc1[mt][nt] = __builtin_amdgcn_mfma_f32_16x16x32_bf16(ah, bl[nt], acc1[mt][nt], 0, 0, 0);
                acc1[mt][nt] = __builtin_amdgcn_mfma_f32_16x16x32_bf16(al, bh[nt], acc1[mt][nt], 0, 0, 0);
            }
        }
    }
    __syncthreads();   // xs reads complete before hs overwrite

    // ---- h epilogue: relu(acc1 + bv) -> split bf16 -> LDS (hs) ----
    // C/D frag: col = l15 (token), row-in-tile = hi*4 + r  [m89]
    #pragma unroll
    for (int mt = 0; mt < 4; ++mt) {
        const int ff0 = w * 64 + mt * 16 + hi * 4;
        float4 bia = *(const float4*)&bv[ff0];
        const float bb[4] = {bia.x, bia.y, bia.z, bia.w};
        const int kg = ff0 >> 3;
        const int jo = (hi & 1) * 4;
        #pragma unroll
        for (int nt = 0; nt < 2; ++nt) {
            const int tok = nt * 16 + l15;
            u16 hh[4], hl[4];
            #pragma unroll
            for (int r = 0; r < 4; ++r) {
                float v = fmaxf(acc1[mt][nt][r] + bb[r], 0.f);
                hh[r] = f2bf(v);
                hl[r] = f2bf(v - bf2f(hh[r]));
            }
            const int e = (kg * 32 + tok) * 8 + jo;
            *(ushort4*)&hsh[e] = (ushort4){hh[0], hh[1], hh[2], hh[3]};
            *(ushort4*)&hsl[e] = (ushort4){hl[0], hl[1], hl[2], hl[3]};
        }
    }
    __syncthreads();

    // ---- GEMM2: y[256][32] = Wo * h, K=512 (16 k-steps); wave w: rows w*32.. ----
    f32x4 acc2[2][2];
    #pragma unroll
    for (int mt = 0; mt < 2; ++mt)
        #pragma unroll
        for (int nt = 0; nt < 2; ++nt)
            acc2[mt][nt] = (f32x4){0.f, 0.f, 0.f, 0.f};

    #pragma unroll 2
    for (int ks = 0; ks < 16; ++ks) {
        bf16x8 bh[2], bl[2];
        #pragma unroll
        for (int nt = 0; nt < 2; ++nt) {
            const int g = (ks * 4 + hi) * 32 + nt * 16 + l15;
            bh[nt] = *(const bf16x8*)&hsh[g * 8];
            bl[nt] = *(const bf16x8*)&hsl[g * 8];
        }
        #pragma unroll
        for (int mt = 0; mt < 2; ++mt) {
            const size_t g = ((size_t)(w * 2 + mt) * 64 + ks * 4 + hi) * 16 + l15;
            bf16x8 ah = *(const bf16x8*)&Woh[g * 8];
            bf16x8 al = *(const bf16x8*)&Wol[g * 8];
            #pragma unroll
            for (int nt = 0; nt < 2; ++nt) {
                acc2[mt][nt] = __builtin_amdgcn_mfma_f32_16x16x32_bf16(ah, bh[nt], acc2[mt][nt], 0, 0, 0);
                acc2[mt][nt] = __builtin_amdgcn_mfma_f32_16x16x32_bf16(ah, bl[nt], acc2[mt][nt], 0, 0, 0);
                acc2[mt][nt] = __builtin_amdgcn_mfma_f32_16x16x32_bf16(al, bh[nt], acc2[mt][nt], 0, 0, 0);
            }
        }
    }
    __syncthreads();   // hs reads complete before os overwrite

    // ---- out epilogue: relu(acc2 + bo) -> os (LDS transpose) ----
    #pragma unroll
    for (int mt = 0; mt < 2; ++mt) {
        const int ch0 = w * 32 + mt * 16 + hi * 4;
        float4 bia = *(const float4*)&bo[ch0];
        const float bb[4] = {bia.x, bia.y, bia.z, bia.w};
        #pragma unroll
        for (int nt = 0; nt < 2; ++nt) {
            const int tok = nt * 16 + l15;
            #pragma unroll
            for (int r = 0; r < 4; ++r)
                os[(ch0 + r) * OSP + tok] = fmaxf(acc2[mt][nt][r] + bb[r], 0.f);
        }
    }
    __syncthreads();

    // ---- final: out = os + x (coalesced float4), BN partial sums ----
    const int tok4 = (t & 7) * 4;       // 8 float4 positions over 32 tokens
    const int chb  = t >> 3;            // 0..63
    #pragma unroll
    for (int ii = 0; ii < 4; ++ii) {
        const int ch = chb + ii * 64;
        float4 o = *(float4*)&os[ch * OSP + tok4];
        const size_t goff = ((size_t)b * COUT + ch) * NTOT + n0 + tok4;
        float4 rx = *(const float4*)&x[goff];
        float4 v = {o.x + rx.x, o.y + rx.y, o.z + rx.z, o.w + rx.w};
        *(float4*)&out[goff] = v;
        float s  = v.x + v.y + v.z + v.w;
        float s2 = v.x * v.x + v.y * v.y + v.z * v.z + v.w * v.w;
        #pragma unroll
        for (int off = 1; off < 8; off <<= 1) {
            s  += __shfl_xor(s, off);
            s2 += __shfl_xor(s2, off);
        }
        if ((t & 7) == 0) {
            atomicAdd(&stats[ch], s);
            atomicAdd(&stats[COUT + ch], s2);
        }
    }
}

// ---------------------------------------------------------------------------
// BN normalize (stats = per-channel sum / sumsq over B*N).
// ---------------------------------------------------------------------------
__global__ __launch_bounds__(256)
void bn_norm(float* __restrict__ out, const float* __restrict__ stats,
             const float* __restrict__ gamma, const float* __restrict__ beta)
{
    const int i4 = blockIdx.x * 256 + threadIdx.x;
    const int c = (i4 >> 10) & (COUT - 1);
    const float inv = 1.0f / (NB * NTOT);
    const float mean = stats[c] * inv;
    const float var  = stats[COUT + c] * inv - mean * mean;
    const float sc = gamma[c] * rsqrtf(var + BN_EPS);
    const float sh = beta[c] - mean * sc;
    float4 v = reinterpret_cast<float4*>(out)[i4];
    v.x = v.x * sc + sh;
    v.y = v.y * sc + sh;
    v.z = v.z * sc + sh;
    v.w = v.w * sc + sh;
    reinterpret_cast<float4*>(out)[i4] = v;
}

extern "C" void kernel_launch(void* const* d_in, const int* in_sizes, int n_in,
                              void* d_out, int out_size, void* d_ws, size_t ws_size,
                              hipStream_t stream)
{
    const float* x     = (const float*)d_in[0];
    // d_in[1..4] = Wk, bk, Wq, bq — dead (softmax rowsum == 1)
    const float* Wv    = (const float*)d_in[5];
    const float* bv    = (const float*)d_in[6];
    const float* Wo    = (const float*)d_in[7];
    const float* bo    = (const float*)d_in[8];
    const float* gamma = (const float*)d_in[9];
    const float* beta  = (const float*)d_in[10];
    float* out = (float*)d_out;

    // workspace layout (~17.8 MB)
    u16* xh   = (u16*)d_ws;
    u16* xl   = xh  + (size_t)NB * NTOT * CIN;
    u16* Wvh  = xl  + (size_t)NB * NTOT * CIN;
    u16* Wvl  = Wvh + (size_t)FF * CIN;
    u16* Woh  = Wvl + (size_t)FF * CIN;
    u16* Wol  = Woh + (size_t)COUT * FF;
    float* stats = (float*)(Wol + (size_t)COUT * FF);

    prep_weights<<<128, 256, 0, stream>>>(Wv, Wo, Wvh, Wvl, Woh, Wol, stats);
    pack_x<<<NB * 64, 256, 0, stream>>>(x, xh, xl);
    fused_mlp<<<NB * 128, 512, 0, stream>>>(xh, xl, Wvh, Wvl, Woh, Wol,
                                            bv, bo, x, out, stats);
    bn_norm<<<(NB * COUT * NTOT / 4) / 256, 256, 0, stream>>>(out, stats, gamma, beta);
}

// Round 11
// 158.978 us; speedup vs baseline: 1.3826x; 1.0078x over previous
//
#include <hip/hip_runtime.h>

// Problem constants
#define NTOT 4096      // T*H*W = 16^3
#define NB   4
#define CIN  256
#define FF   512
#define COUT 256
#define BN_EPS 1e-5f
#define NT_B 32        // tokens per fused block
#define OSP  36        // padded out-stage row stride (f32)

typedef __attribute__((ext_vector_type(8))) short bf16x8;  // 8 bf16 = 16 B
typedef __attribute__((ext_vector_type(4))) float f32x4;
typedef unsigned short u16;

#define MFMA16(A, B, C) __builtin_amdgcn_mfma_f32_16x16x32_bf16((A), (B), (C), 0, 0, 0)

__device__ __forceinline__ u16 f2bf(float f) {
    unsigned u = __float_as_uint(f);
    u += 0x7fffu + ((u >> 16) & 1u);   // round-to-nearest-even
    return (u16)(u >> 16);
}
__device__ __forceinline__ float bf2f(u16 h) {
    return __uint_as_float(((unsigned)h) << 16);
}

// ---------------------------------------------------------------------------
// Weights -> packed split-bf16 granule layout + zero BN stats.
// Granule g = ((m>>4)*NKG + kg)*16 + (m&15); elems g*8+j = W[m][kg*8+j].
// ---------------------------------------------------------------------------
__global__ __launch_bounds__(256)
void prep_weights(const float* __restrict__ Wv, const float* __restrict__ Wo,
                  u16* __restrict__ Wvh, u16* __restrict__ Wvl,
                  u16* __restrict__ Woh, u16* __restrict__ Wol,
                  float* __restrict__ stats)
{
    const int t = threadIdx.x;
    const int g = blockIdx.x * 256 + t;
    if (blockIdx.x == 0) { stats[t] = 0.f; stats[256 + t] = 0.f; }

    const float* src; u16 *dh, *dl; int m, kg, K;
    if (g < 16384) { m = g >> 5;           kg = g & 31; K = CIN; src = Wv; dh = Wvh; dl = Wvl; }
    else           { int g2 = g - 16384; m = g2 >> 6; kg = g2 & 63; K = FF;  src = Wo; dh = Woh; dl = Wol; }

    const int nkg = K >> 3;
    const size_t gran = ((size_t)(m >> 4) * nkg + kg) * 16 + (m & 15);
    float4 v0 = *(const float4*)&src[(size_t)m * K + kg * 8];
    float4 v1 = *(const float4*)&src[(size_t)m * K + kg * 8 + 4];
    const float f[8] = {v0.x, v0.y, v0.z, v0.w, v1.x, v1.y, v1.z, v1.w};
    u16 h[8], l[8];
    #pragma unroll
    for (int j = 0; j < 8; ++j) { h[j] = f2bf(f[j]); l[j] = f2bf(f[j] - bf2f(h[j])); }
    bf16x8 hv = {(short)h[0],(short)h[1],(short)h[2],(short)h[3],(short)h[4],(short)h[5],(short)h[6],(short)h[7]};
    bf16x8 lv = {(short)l[0],(short)l[1],(short)l[2],(short)l[3],(short)l[4],(short)l[5],(short)l[6],(short)l[7]};
    *(bf16x8*)&dh[gran * 8] = hv;
    *(bf16x8*)&dl[gran * 8] = lv;
}

// ---------------------------------------------------------------------------
// x [b][c][n] fp32 -> packed split planes in 32-token sub-blocks:
//   e = (((b*128 + tb2)*32 + kg)*32 + tok32)*8 ; elem j = x[b][kg*8+j][tb2*32+tok32]
// ---------------------------------------------------------------------------
__global__ __launch_bounds__(256)
void pack_x(const float* __restrict__ x, u16* __restrict__ xh, u16* __restrict__ xl)
{
    __shared__ float xt[CIN][68];   // 64 tokens + pad
    const int t = threadIdx.x;
    const int b = blockIdx.x >> 6, tb = blockIdx.x & 63;
    const int n0 = tb * 64;
    const int c16 = t >> 4, tok4 = (t & 15) * 4;

    #pragma unroll
    for (int rr = 0; rr < 16; ++rr) {
        const int c = rr * 16 + c16;
        float4 v = *(const float4*)&x[((size_t)b * CIN + c) * NTOT + n0 + tok4];
        *(float4*)&xt[c][tok4] = v;
    }
    __syncthreads();

    const int tok = t & 63, wq = t >> 6;
    const int sb = tok >> 5, tok32 = tok & 31;
    #pragma unroll
    for (int r = 0; r < 8; ++r) {
        const int kg = r * 4 + wq;
        u16 h8[8], l8[8];
        #pragma unroll
        for (int j = 0; j < 8; ++j) {
            float f = xt[kg * 8 + j][tok];
            h8[j] = f2bf(f);
            l8[j] = f2bf(f - bf2f(h8[j]));
        }
        const size_t e = ((((size_t)(b * 128 + tb * 2 + sb)) * 32 + kg) * 32 + tok32) * 8;
        bf16x8 hv = {(short)h8[0],(short)h8[1],(short)h8[2],(short)h8[3],(short)h8[4],(short)h8[5],(short)h8[6],(short)h8[7]};
        bf16x8 lv = {(short)l8[0],(short)l8[1],(short)l8[2],(short)l8[3],(short)l8[4],(short)l8[5],(short)l8[6],(short)l8[7]};
        *(bf16x8*)&xh[e] = hv;
        *(bf16x8*)&xl[e] = lv;
    }
}

// ---------------------------------------------------------------------------
// Fused MLP: 32 tokens/block, 8 waves (512 thr), 64 KB LDS -> 2 blocks/CU.
// Software-pipelined GEMM cores: statically ping-ponged register double
// buffers for weights (global/L2) and B-fragments (LDS); prefetch issued
// before each MFMA cluster so load latency hides under matrix work.
// ---------------------------------------------------------------------------
__global__ __launch_bounds__(512, 4)
void fused_mlp(const u16* __restrict__ xh, const u16* __restrict__ xl,
               const u16* __restrict__ Wvh, const u16* __restrict__ Wvl,
               const u16* __restrict__ Woh, const u16* __restrict__ Wol,
               const float* __restrict__ bv, const float* __restrict__ bo,
               const float* __restrict__ x, float* __restrict__ out,
               float* __restrict__ stats)
{
    __shared__ __align__(16) unsigned char smem[65536];
    u16*   xsh = (u16*)smem;               // 16 KB  (phase A)
    u16*   xsl = (u16*)(smem + 16384);     // 16 KB
    u16*   hsh = (u16*)smem;               // 32 KB  (phase B, overwrites xs)
    u16*   hsl = (u16*)(smem + 32768);     // 32 KB
    float* os  = (float*)smem;             // 256 x OSP f32 = 36 KB (phase C)

    const int t   = threadIdx.x;
    const int b   = blockIdx.x >> 7;        // 128 token-blocks per batch
    const int tb2 = blockIdx.x & 127;
    const int n0  = tb2 * NT_B;
    const int ln  = t & 63, w = t >> 6;     // 8 waves
    const int l15 = ln & 15, hi = ln >> 4;

    // ---- stage x tile (32 KB linear copy, 16 B/lane) ----
    const size_t xbase = ((size_t)(b * 128 + tb2)) * 8192;   // u16 per plane-block
    #pragma unroll
    for (int i = 0; i < 2; ++i) {
        const int e = (i * 512 + t) * 8;
        *(bf16x8*)&xsh[e] = *(const bf16x8*)&xh[xbase + e];
        *(bf16x8*)&xsl[e] = *(const bf16x8*)&xl[xbase + e];
    }

    // ============== GEMM1: h[512][32] = Wv * x, K=256 ==============
    // wave w owns rows w*64 .. w*64+63 (4 m-tiles), pipelined in half-ks
    // steps of 2 m-tiles; 16 steps total.
    f32x4 acc1[4][2];
    #pragma unroll
    for (int mt = 0; mt < 4; ++mt)
        #pragma unroll
        for (int nt = 0; nt < 2; ++nt)
            acc1[mt][nt] = (f32x4){0.f, 0.f, 0.f, 0.f};

#define LDW1(KS, P, WH, WL) do { _Pragma("unroll")                              \
    for (int i_ = 0; i_ < 2; ++i_) {                                            \
        const int mt_ = (P) * 2 + i_;                                           \
        const size_t g_ = ((size_t)(w * 4 + mt_) * 32 + (KS) * 4 + hi) * 16 + l15; \
        WH[i_] = *(const bf16x8*)&Wvh[g_ * 8];                                  \
        WL[i_] = *(const bf16x8*)&Wvl[g_ * 8];                                  \
    } } while (0)
#define LDB1(KS, BH, BL) do { _Pragma("unroll")                                 \
    for (int nt_ = 0; nt_ < 2; ++nt_) {                                         \
        const int g_ = ((KS) * 4 + hi) * 32 + nt_ * 16 + l15;                   \
        BH[nt_] = *(const bf16x8*)&xsh[g_ * 8];                                 \
        BL[nt_] = *(const bf16x8*)&xsl[g_ * 8];                                 \
    } } while (0)
#define MM1(P, WH, WL, BH, BL) do { _Pragma("unroll")                           \
    for (int i_ = 0; i_ < 2; ++i_) { _Pragma("unroll")                          \
        for (int nt_ = 0; nt_ < 2; ++nt_) {                                     \
            acc1[(P)*2+i_][nt_] = MFMA16(WH[i_], BH[nt_], acc1[(P)*2+i_][nt_]); \
            acc1[(P)*2+i_][nt_] = MFMA16(WH[i_], BL[nt_], acc1[(P)*2+i_][nt_]); \
            acc1[(P)*2+i_][nt_] = MFMA16(WL[i_], BH[nt_], acc1[(P)*2+i_][nt_]); \
    } } } while (0)

    bf16x8 w1hA[2], w1lA[2], w1hB[2], w1lB[2];
    bf16x8 b1hE[2], b1lE[2], b1hO[2], b1lO[2];

    LDW1(0, 0, w1hA, w1lA);      // weight prologue overlaps staging stores
    __syncthreads();             // xs visible
    LDB1(0, b1hE, b1lE);

    #pragma unroll
    for (int s = 0; s < 16; ++s) {
        const int ks = s >> 1, p = s & 1;
        // prefetch next step before this step's MFMAs
        if (p == 0) {
            LDW1(ks, 1, w1hB, w1lB);
        } else if (ks < 7) {
            LDW1(ks + 1, 0, w1hA, w1lA);
            if (ks & 1) { LDB1(ks + 1, b1hE, b1lE); }
            else        { LDB1(ks + 1, b1hO, b1lO); }
        }
        if (p == 0) {
            if (ks & 1) MM1(0, w1hA, w1lA, b1hO, b1lO);
            else        MM1(0, w1hA, w1lA, b1hE, b1lE);
        } else {
            if (ks & 1) MM1(1, w1hB, w1lB, b1hO, b1lO);
            else        MM1(1, w1hB, w1lB, b1hE, b1lE);
        }
    }
#undef LDW1
#undef LDB1
#undef MM1

    // GEMM2 weight prologue (global; independent of LDS phase change)
#define LDW2(KS, WH, WL) do { _Pragma("unroll")                                 \
    for (int mt_ = 0; mt_ < 2; ++mt_) {                                         \
        const size_t g_ = ((size_t)(w * 2 + mt_) * 64 + (KS) * 4 + hi) * 16 + l15; \
        WH[mt_] = *(const bf16x8*)&Woh[g_ * 8];                                 \
        WL[mt_] = *(const bf16x8*)&Wol[g_ * 8];                                 \
    } } while (0)
#define LDB2(KS, BH, BL) do { _Pragma("unroll")                                 \
    for (int nt_ = 0; nt_ < 2; ++nt_) {                                         \
        const int g_ = ((KS) * 4 + hi) * 32 + nt_ * 16 + l15;                   \
        BH[nt_] = *(const bf16x8*)&hsh[g_ * 8];                                 \
        BL[nt_] = *(const bf16x8*)&hsl[g_ * 8];                                 \
    } } while (0)
#define MM2(WH, WL, BH, BL) do { _Pragma("unroll")                              \
    for (int mt_ = 0; mt_ < 2; ++mt_) { _Pragma("unroll")                       \
        for (int nt_ = 0; nt_ < 2; ++nt_) {                                     \
            acc2[mt_][nt_] = MFMA16(WH[mt_], BH[nt_], acc2[mt_][nt_]);          \
            acc2[mt_][nt_] = MFMA16(WH[mt_], BL[nt_], acc2[mt_][nt_]);          \
            acc2[mt_][nt_] = MFMA16(WL[mt_], BH[nt_], acc2[mt_][nt_]);          \
    } } } while (0)

    bf16x8 w2hA[2], w2lA[2], w2hB[2], w2lB[2];
    bf16x8 b2hE[2], b2lE[2], b2hO[2], b2lO[2];
    LDW2(0, w2hA, w2lA);

    __syncthreads();   // xs reads complete before hs overwrite

    // ---- h epilogue: relu(acc1 + bv) -> split bf16 -> LDS (hs) ----
    // C/D frag: col = l15 (token), row-in-tile = hi*4 + r  [m89]
    #pragma unroll
    for (int mt = 0; mt < 4; ++mt) {
        const int ff0 = w * 64 + mt * 16 + hi * 4;
        float4 bia = *(const float4*)&bv[ff0];
        const float bb[4] = {bia.x, bia.y, bia.z, bia.w};
        const int kg = ff0 >> 3;
        const int jo = (hi & 1) * 4;
        #pragma unroll
        for (int nt = 0; nt < 2; ++nt) {
            const int tok = nt * 16 + l15;
            u16 hh[4], hl[4];
            #pragma unroll
            for (int r = 0; r < 4; ++r) {
                float v = fmaxf(acc1[mt][nt][r] + bb[r], 0.f);
                hh[r] = f2bf(v);
                hl[r] = f2bf(v - bf2f(hh[r]));
            }
            const int e = (kg * 32 + tok) * 8 + jo;
            *(ushort4*)&hsh[e] = (ushort4){hh[0], hh[1], hh[2], hh[3]};
            *(ushort4*)&hsl[e] = (ushort4){hl[0], hl[1], hl[2], hl[3]};
        }
    }
    __syncthreads();

    // ============== GEMM2: y[256][32] = Wo * h, K=512 (16 ks) ==============
    f32x4 acc2[2][2];
    #pragma unroll
    for (int mt = 0; mt < 2; ++mt)
        #pragma unroll
        for (int nt = 0; nt < 2; ++nt)
            acc2[mt][nt] = (f32x4){0.f, 0.f, 0.f, 0.f};

    LDB2(0, b2hE, b2lE);
    #pragma unroll
    for (int ks = 0; ks < 16; ++ks) {
        if (ks < 15) {
            if (ks & 1) { LDW2(ks + 1, w2hA, w2lA); LDB2(ks + 1, b2hE, b2lE); }
            else        { LDW2(ks + 1, w2hB, w2lB); LDB2(ks + 1, b2hO, b2lO); }
        }
        if (ks & 1) MM2(w2hB, w2lB, b2hO, b2lO);
        else        MM2(w2hA, w2lA, b2hE, b2lE);
    }
#undef LDW2
#undef LDB2
#undef MM2

    __syncthreads();   // hs reads complete before os overwrite

    // ---- out epilogue: relu(acc2 + bo) -> os (LDS transpose) ----
    #pragma unroll
    for (int mt = 0; mt < 2; ++mt) {
        const int ch0 = w * 32 + mt * 16 + hi * 4;
        float4 bia = *(const float4*)&bo[ch0];
        const float bb[4] = {bia.x, bia.y, bia.z, bia.w};
        #pragma unroll
        for (int nt = 0; nt < 2; ++nt) {
            const int tok = nt * 16 + l15;
            #pragma unroll
            for (int r = 0; r < 4; ++r)
                os[(ch0 + r) * OSP + tok] = fmaxf(acc2[mt][nt][r] + bb[r], 0.f);
        }
    }
    __syncthreads();

    // ---- final: out = os + x (coalesced float4), BN partial sums ----
    const int tok4 = (t & 7) * 4;       // 8 float4 positions over 32 tokens
    const int chb  = t >> 3;            // 0..63
    #pragma unroll
    for (int ii = 0; ii < 4; ++ii) {
        const int ch = chb + ii * 64;
        float4 o = *(float4*)&os[ch * OSP + tok4];
        const size_t goff = ((size_t)b * COUT + ch) * NTOT + n0 + tok4;
        float4 rx = *(const float4*)&x[goff];
        float4 v = {o.x + rx.x, o.y + rx.y, o.z + rx.z, o.w + rx.w};
        *(float4*)&out[goff] = v;
        float s  = v.x + v.y + v.z + v.w;
        float s2 = v.x * v.x + v.y * v.y + v.z * v.z + v.w * v.w;
        #pragma unroll
        for (int off = 1; off < 8; off <<= 1) {
            s  += __shfl_xor(s, off);
            s2 += __shfl_xor(s2, off);
        }
        if ((t & 7) == 0) {
            atomicAdd(&stats[ch], s);
            atomicAdd(&stats[COUT + ch], s2);
        }
    }
}

// ---------------------------------------------------------------------------
// BN normalize (stats = per-channel sum / sumsq over B*N).
// ---------------------------------------------------------------------------
__global__ __launch_bounds__(256)
void bn_norm(float* __restrict__ out, const float* __restrict__ stats,
             const float* __restrict__ gamma, const float* __restrict__ beta)
{
    const int i4 = blockIdx.x * 256 + threadIdx.x;
    const int c = (i4 >> 10) & (COUT - 1);
    const float inv = 1.0f / (NB * NTOT);
    const float mean = stats[c] * inv;
    const float var  = stats[COUT + c] * inv - mean * mean;
    const float sc = gamma[c] * rsqrtf(var + BN_EPS);
    const float sh = beta[c] - mean * sc;
    float4 v = reinterpret_cast<float4*>(out)[i4];
    v.x = v.x * sc + sh;
    v.y = v.y * sc + sh;
    v.z = v.z * sc + sh;
    v.w = v.w * sc + sh;
    reinterpret_cast<float4*>(out)[i4] = v;
}

extern "C" void kernel_launch(void* const* d_in, const int* in_sizes, int n_in,
                              void* d_out, int out_size, void* d_ws, size_t ws_size,
                              hipStream_t stream)
{
    const float* x     = (const float*)d_in[0];
    // d_in[1..4] = Wk, bk, Wq, bq — dead (softmax rowsum == 1)
    const float* Wv    = (const float*)d_in[5];
    const float* bv    = (const float*)d_in[6];
    const float* Wo    = (const float*)d_in[7];
    const float* bo    = (const float*)d_in[8];
    const float* gamma = (const float*)d_in[9];
    const float* beta  = (const float*)d_in[10];
    float* out = (float*)d_out;

    // workspace layout (~17.8 MB)
    u16* xh   = (u16*)d_ws;
    u16* xl   = xh  + (size_t)NB * NTOT * CIN;
    u16* Wvh  = xl  + (size_t)NB * NTOT * CIN;
    u16* Wvl  = Wvh + (size_t)FF * CIN;
    u16* Woh  = Wvl + (size_t)FF * CIN;
    u16* Wol  = Woh + (size_t)COUT * FF;
    float* stats = (float*)(Wol + (size_t)COUT * FF);

    prep_weights<<<128, 256, 0, stream>>>(Wv, Wo, Wvh, Wvl, Woh, Wol, stats);
    pack_x<<<NB * 64, 256, 0, stream>>>(x, xh, xl);
    fused_mlp<<<NB * 128, 512, 0, stream>>>(xh, xl, Wvh, Wvl, Woh, Wol,
                                            bv, bo, x, out, stats);
    bn_norm<<<(NB * COUT * NTOT / 4) / 256, 256, 0, stream>>>(out, stats, gamma, beta);
}

// Round 13
// 152.189 us; speedup vs baseline: 1.4443x; 1.0446x over previous
//
#include <hip/hip_runtime.h>

// Problem constants
#define NTOT 4096      // T*H*W = 16^3
#define NB   4
#define CIN  256
#define FF   512
#define COUT 256
#define BN_EPS 1e-5f
#define NT_B 32        // tokens per fused block
#define OSP  36        // padded out-stage row stride (f32)

typedef __attribute__((ext_vector_type(8))) short bf16x8;  // 8 bf16 = 16 B
typedef __attribute__((ext_vector_type(4))) float f32x4;
typedef unsigned short u16;

#define MFMA16(A, B, C) __builtin_amdgcn_mfma_f32_16x16x32_bf16((A), (B), (C), 0, 0, 0)

__device__ __forceinline__ u16 f2bf(float f) {
    unsigned u = __float_as_uint(f);
    u += 0x7fffu + ((u >> 16) & 1u);   // round-to-nearest-even
    return (u16)(u >> 16);
}
__device__ __forceinline__ float bf2f(u16 h) {
    return __uint_as_float(((unsigned)h) << 16);
}

// ---------------------------------------------------------------------------
// Weights -> packed split-bf16 granule layout + zero BN stats.
// Granule g = ((m>>4)*NKG + kg)*16 + (m&15); elems g*8+j = W[m][kg*8+j].
// ---------------------------------------------------------------------------
__global__ __launch_bounds__(256)
void prep_weights(const float* __restrict__ Wv, const float* __restrict__ Wo,
                  u16* __restrict__ Wvh, u16* __restrict__ Wvl,
                  u16* __restrict__ Woh, u16* __restrict__ Wol,
                  float* __restrict__ stats)
{
    const int t = threadIdx.x;
    const int g = blockIdx.x * 256 + t;
    if (blockIdx.x == 0) { stats[t] = 0.f; stats[256 + t] = 0.f; }

    const float* src; u16 *dh, *dl; int m, kg, K;
    if (g < 16384) { m = g >> 5;           kg = g & 31; K = CIN; src = Wv; dh = Wvh; dl = Wvl; }
    else           { int g2 = g - 16384; m = g2 >> 6; kg = g2 & 63; K = FF;  src = Wo; dh = Woh; dl = Wol; }

    const int nkg = K >> 3;
    const size_t gran = ((size_t)(m >> 4) * nkg + kg) * 16 + (m & 15);
    float4 v0 = *(const float4*)&src[(size_t)m * K + kg * 8];
    float4 v1 = *(const float4*)&src[(size_t)m * K + kg * 8 + 4];
    const float f[8] = {v0.x, v0.y, v0.z, v0.w, v1.x, v1.y, v1.z, v1.w};
    u16 h[8], l[8];
    #pragma unroll
    for (int j = 0; j < 8; ++j) { h[j] = f2bf(f[j]); l[j] = f2bf(f[j] - bf2f(h[j])); }
    bf16x8 hv = {(short)h[0],(short)h[1],(short)h[2],(short)h[3],(short)h[4],(short)h[5],(short)h[6],(short)h[7]};
    bf16x8 lv = {(short)l[0],(short)l[1],(short)l[2],(short)l[3],(short)l[4],(short)l[5],(short)l[6],(short)l[7]};
    *(bf16x8*)&dh[gran * 8] = hv;
    *(bf16x8*)&dl[gran * 8] = lv;
}

// ---------------------------------------------------------------------------
// Fused MLP with in-LDS transpose/split of x (pack_x eliminated):
// stage x fp32 [256][32] -> transpose+split -> GEMM1 -> GEMM2 ->
// residual + BN stats. 512 blocks x 512 thr, 64 KB LDS -> 2 blocks/CU.
// ---------------------------------------------------------------------------
__global__ __launch_bounds__(512, 4)
void fused_mlp(const float* __restrict__ x,
               const u16* __restrict__ Wvh, const u16* __restrict__ Wvl,
               const u16* __restrict__ Woh, const u16* __restrict__ Wol,
               const float* __restrict__ bv, const float* __restrict__ bo,
               float* __restrict__ out, float* __restrict__ stats)
{
    __shared__ __align__(16) unsigned char smem[65536];
    float* xt  = (float*)smem;               // 32 KB  fp32 x tile [c][tok] (phase A0)
    u16*   xsh = (u16*)(smem + 32768);       // 16 KB  split x (phase A)
    u16*   xsl = (u16*)(smem + 49152);       // 16 KB
    u16*   hsh = (u16*)smem;                 // 32 KB  split h (phase B, overlays xt)
    u16*   hsl = (u16*)(smem + 32768);       // 32 KB  (overlays xs after GEMM1)
    float* os  = (float*)smem;               // 256 x OSP f32 = 36 KB (phase C)

    const int t   = threadIdx.x;
    const int b   = blockIdx.x >> 7;         // 128 token-blocks per batch
    const int tb2 = blockIdx.x & 127;
    const int n0  = tb2 * NT_B;
    const int ln  = t & 63, w = t >> 6;      // 8 waves
    const int l15 = ln & 15, hi = ln >> 4;

    // ---- phase A0: stage x fp32 [256][32] (coalesced 128B row segments) ----
    #pragma unroll
    for (int i = 0; i < 4; ++i) {
        const int f4 = t + i * 512;          // 2048 float4s
        const int c = f4 >> 3, col4 = (f4 & 7) * 4;
        float4 v = *(const float4*)&x[((size_t)b * CIN + c) * NTOT + n0 + col4];
        *(float4*)&xt[c * NT_B + col4] = v;
    }

    // GEMM1 weight prologue (global only; overlaps staging)
#define LDW1(KS, P, WH, WL) do { _Pragma("unroll")                              \
    for (int i_ = 0; i_ < 2; ++i_) {                                            \
        const int mt_ = (P) * 2 + i_;                                           \
        const size_t g_ = ((size_t)(w * 4 + mt_) * 32 + (KS) * 4 + hi) * 16 + l15; \
        WH[i_] = *(const bf16x8*)&Wvh[g_ * 8];                                  \
        WL[i_] = *(const bf16x8*)&Wvl[g_ * 8];                                  \
    } } while (0)

    bf16x8 w1hA[2], w1lA[2], w1hB[2], w1lB[2];
    LDW1(0, 0, w1hA, w1lA);
    __syncthreads();

    // ---- phase A1: transpose+split xt -> xs granules (kg*32+tok) ----
    {
        const int tok = t & 31, kg0 = t >> 5;    // kg0 0..15
        #pragma unroll
        for (int i = 0; i < 2; ++i) {
            const int kg = kg0 + i * 16;
            u16 h8[8], l8[8];
            #pragma unroll
            for (int j = 0; j < 8; ++j) {
                float f = xt[(kg * 8 + j) * NT_B + tok];
                h8[j] = f2bf(f);
                l8[j] = f2bf(f - bf2f(h8[j]));
            }
            const int e = (kg * 32 + tok) * 8;
            bf16x8 hv = {(short)h8[0],(short)h8[1],(short)h8[2],(short)h8[3],(short)h8[4],(short)h8[5],(short)h8[6],(short)h8[7]};
            bf16x8 lv = {(short)l8[0],(short)l8[1],(short)l8[2],(short)l8[3],(short)l8[4],(short)l8[5],(short)l8[6],(short)l8[7]};
            *(bf16x8*)&xsh[e] = hv;
            *(bf16x8*)&xsl[e] = lv;
        }
    }
    __syncthreads();

    // ============== GEMM1: h[512][32] = Wv * x, K=256 ==============
    f32x4 acc1[4][2];
    #pragma unroll
    for (int mt = 0; mt < 4; ++mt)
        #pragma unroll
        for (int nt = 0; nt < 2; ++nt)
            acc1[mt][nt] = (f32x4){0.f, 0.f, 0.f, 0.f};

#define LDB1(KS, BH, BL) do { _Pragma("unroll")                                 \
    for (int nt_ = 0; nt_ < 2; ++nt_) {                                         \
        const int g_ = ((KS) * 4 + hi) * 32 + nt_ * 16 + l15;                   \
        BH[nt_] = *(const bf16x8*)&xsh[g_ * 8];                                 \
        BL[nt_] = *(const bf16x8*)&xsl[g_ * 8];                                 \
    } } while (0)
#define MM1(P, WH, WL, BH, BL) do { _Pragma("unroll")                           \
    for (int i_ = 0; i_ < 2; ++i_) { _Pragma("unroll")                          \
        for (int nt_ = 0; nt_ < 2; ++nt_) {                                     \
            acc1[(P)*2+i_][nt_] = MFMA16(WH[i_], BH[nt_], acc1[(P)*2+i_][nt_]); \
            acc1[(P)*2+i_][nt_] = MFMA16(WH[i_], BL[nt_], acc1[(P)*2+i_][nt_]); \
            acc1[(P)*2+i_][nt_] = MFMA16(WL[i_], BH[nt_], acc1[(P)*2+i_][nt_]); \
    } } } while (0)

    bf16x8 b1hE[2], b1lE[2], b1hO[2], b1lO[2];
    LDB1(0, b1hE, b1lE);

    #pragma unroll
    for (int s = 0; s < 16; ++s) {
        const int ks = s >> 1, p = s & 1;
        if (p == 0) {
            LDW1(ks, 1, w1hB, w1lB);
        } else if (ks < 7) {
            LDW1(ks + 1, 0, w1hA, w1lA);
            if (ks & 1) { LDB1(ks + 1, b1hE, b1lE); }
            else        { LDB1(ks + 1, b1hO, b1lO); }
        }
        if (p == 0) {
            if (ks & 1) MM1(0, w1hA, w1lA, b1hO, b1lO);
            else        MM1(0, w1hA, w1lA, b1hE, b1lE);
        } else {
            if (ks & 1) MM1(1, w1hB, w1lB, b1hO, b1lO);
            else        MM1(1, w1hB, w1lB, b1hE, b1lE);
        }
    }
#undef LDW1
#undef LDB1
#undef MM1

    // GEMM2 weight prologue
#define LDW2(KS, WH, WL) do { _Pragma("unroll")                                 \
    for (int mt_ = 0; mt_ < 2; ++mt_) {                                         \
        const size_t g_ = ((size_t)(w * 2 + mt_) * 64 + (KS) * 4 + hi) * 16 + l15; \
        WH[mt_] = *(const bf16x8*)&Woh[g_ * 8];                                 \
        WL[mt_] = *(const bf16x8*)&Wol[g_ * 8];                                 \
    } } while (0)
#define LDB2(KS, BH, BL) do { _Pragma("unroll")                                 \
    for (int nt_ = 0; nt_ < 2; ++nt_) {                                         \
        const int g_ = ((KS) * 4 + hi) * 32 + nt_ * 16 + l15;                   \
        BH[nt_] = *(const bf16x8*)&hsh[g_ * 8];                                 \
        BL[nt_] = *(const bf16x8*)&hsl[g_ * 8];                                 \
    } } while (0)
#define MM2(WH, WL, BH, BL) do { _Pragma("unroll")                              \
    for (int mt_ = 0; mt_ < 2; ++mt_) { _Pragma("unroll")                       \
        for (int nt_ = 0; nt_ < 2; ++nt_) {                                     \
            acc2[mt_][nt_] = MFMA16(WH[mt_], BH[nt_], acc2[mt_][nt_]);          \
            acc2[mt_][nt_] = MFMA16(WH[mt_], BL[nt_], acc2[mt_][nt_]);          \
            acc2[mt_][nt_] = MFMA16(WL[mt_], BH[nt_], acc2[mt_][nt_]);          \
    } } } while (0)

    bf16x8 w2hA[2], w2lA[2], w2hB[2], w2lB[2];
    bf16x8 b2hE[2], b2lE[2], b2hO[2], b2lO[2];
    LDW2(0, w2hA, w2lA);

    __syncthreads();   // xs reads complete before hs overwrite

    // ---- h epilogue: relu(acc1 + bv) -> split bf16 -> LDS (hs) ----
    // C/D frag: col = l15 (token), row-in-tile = hi*4 + r  [m89]
    #pragma unroll
    for (int mt = 0; mt < 4; ++mt) {
        const int ff0 = w * 64 + mt * 16 + hi * 4;
        float4 bia = *(const float4*)&bv[ff0];
        const float bb[4] = {bia.x, bia.y, bia.z, bia.w};
        const int kg = ff0 >> 3;
        const int jo = (hi & 1) * 4;
        #pragma unroll
        for (int nt = 0; nt < 2; ++nt) {
            const int tok = nt * 16 + l15;
            u16 hh[4], hl[4];
            #pragma unroll
            for (int r = 0; r < 4; ++r) {
                float v = fmaxf(acc1[mt][nt][r] + bb[r], 0.f);
                hh[r] = f2bf(v);
                hl[r] = f2bf(v - bf2f(hh[r]));
            }
            const int e = (kg * 32 + tok) * 8 + jo;
            *(ushort4*)&hsh[e] = (ushort4){hh[0], hh[1], hh[2], hh[3]};
            *(ushort4*)&hsl[e] = (ushort4){hl[0], hl[1], hl[2], hl[3]};
        }
    }
    __syncthreads();

    // ============== GEMM2: y[256][32] = Wo * h, K=512 (16 ks) ==============
    f32x4 acc2[2][2];
    #pragma unroll
    for (int mt = 0; mt < 2; ++mt)
        #pragma unroll
        for (int nt = 0; nt < 2; ++nt)
            acc2[mt][nt] = (f32x4){0.f, 0.f, 0.f, 0.f};

    LDB2(0, b2hE, b2lE);
    #pragma unroll
    for (int ks = 0; ks < 16; ++ks) {
        if (ks < 15) {
            if (ks & 1) { LDW2(ks + 1, w2hA, w2lA); LDB2(ks + 1, b2hE, b2lE); }
            else        { LDW2(ks + 1, w2hB, w2lB); LDB2(ks + 1, b2hO, b2lO); }
        }
        if (ks & 1) MM2(w2hB, w2lB, b2hO, b2lO);
        else        MM2(w2hA, w2lA, b2hE, b2lE);
    }
#undef LDW2
#undef LDB2
#undef MM2

    __syncthreads();   // hs reads complete before os overwrite

    // ---- out epilogue: relu(acc2 + bo) -> os (LDS transpose) ----
    #pragma unroll
    for (int mt = 0; mt < 2; ++mt) {
        const int ch0 = w * 32 + mt * 16 + hi * 4;
        float4 bia = *(const float4*)&bo[ch0];
        const float bb[4] = {bia.x, bia.y, bia.z, bia.w};
        #pragma unroll
        for (int nt = 0; nt < 2; ++nt) {
            const int tok = nt * 16 + l15;
            #pragma unroll
            for (int r = 0; r < 4; ++r)
                os[(ch0 + r) * OSP + tok] = fmaxf(acc2[mt][nt][r] + bb[r], 0.f);
        }
    }
    __syncthreads();

    // ---- final: out = os + x (coalesced float4), BN partial sums ----
    const int tok4 = (t & 7) * 4;       // 8 float4 positions over 32 tokens
    const int chb  = t >> 3;            // 0..63
    #pragma unroll
    for (int ii = 0; ii < 4; ++ii) {
        const int ch = chb + ii * 64;
        float4 o = *(float4*)&os[ch * OSP + tok4];
        const size_t goff = ((size_t)b * COUT + ch) * NTOT + n0 + tok4;
        float4 rx = *(const float4*)&x[goff];
        float4 v = {o.x + rx.x, o.y + rx.y, o.z + rx.z, o.w + rx.w};
        *(float4*)&out[goff] = v;
        float s  = v.x + v.y + v.z + v.w;
        float s2 = v.x * v.x + v.y * v.y + v.z * v.z + v.w * v.w;
        #pragma unroll
        for (int off = 1; off < 8; off <<= 1) {
            s  += __shfl_xor(s, off);
            s2 += __shfl_xor(s2, off);
        }
        if ((t & 7) == 0) {
            atomicAdd(&stats[ch], s);
            atomicAdd(&stats[COUT + ch], s2);
        }
    }
}

// ---------------------------------------------------------------------------
// BN normalize (stats = per-channel sum / sumsq over B*N).
// ---------------------------------------------------------------------------
__global__ __launch_bounds__(256)
void bn_norm(float* __restrict__ out, const float* __restrict__ stats,
             const float* __restrict__ gamma, const float* __restrict__ beta)
{
    const int i4 = blockIdx.x * 256 + threadIdx.x;
    const int c = (i4 >> 10) & (COUT - 1);
    const float inv = 1.0f / (NB * NTOT);
    const float mean = stats[c] * inv;
    const float var  = stats[COUT + c] * inv - mean * mean;
    const float sc = gamma[c] * rsqrtf(var + BN_EPS);
    const float sh = beta[c] - mean * sc;
    float4 v = reinterpret_cast<float4*>(out)[i4];
    v.x = v.x * sc + sh;
    v.y = v.y * sc + sh;
    v.z = v.z * sc + sh;
    v.w = v.w * sc + sh;
    reinterpret_cast<float4*>(out)[i4] = v;
}

extern "C" void kernel_launch(void* const* d_in, const int* in_sizes, int n_in,
                              void* d_out, int out_size, void* d_ws, size_t ws_size,
                              hipStream_t stream)
{
    const float* x     = (const float*)d_in[0];
    // d_in[1..4] = Wk, bk, Wq, bq — dead (softmax rowsum == 1)
    const float* Wv    = (const float*)d_in[5];
    const float* bv    = (const float*)d_in[6];
    const float* Wo    = (const float*)d_in[7];
    const float* bo    = (const float*)d_in[8];
    const float* gamma = (const float*)d_in[9];
    const float* beta  = (const float*)d_in[10];
    float* out = (float*)d_out;

    // workspace: packed weights + stats (~1 MB)
    u16* Wvh  = (u16*)d_ws;
    u16* Wvl  = Wvh + (size_t)FF * CIN;
    u16* Woh  = Wvl + (size_t)FF * CIN;
    u16* Wol  = Woh + (size_t)COUT * FF;
    float* stats = (float*)(Wol + (size_t)COUT * FF);

    prep_weights<<<128, 256, 0, stream>>>(Wv, Wo, Wvh, Wvl, Woh, Wol, stats);
    fused_mlp<<<NB * 128, 512, 0, stream>>>(x, Wvh, Wvl, Woh, Wol,
                                            bv, bo, out, stats);
    bn_norm<<<(NB * COUT * NTOT / 4) / 256, 256, 0, stream>>>(out, stats, gamma, beta);
}